// Round 1
// 614.372 us; speedup vs baseline: 1.0654x; 1.0654x over previous
//
#include <hip/hip_runtime.h>

#ifndef __has_builtin
#define __has_builtin(x) 0
#endif

// Problem constants (fixed by the reference):
constexpr int TN   = 1000;  // T
constexpr int BN   = 4096;  // B
constexpr int HID  = 32;    // hidden dim
constexpr int HH   = 15;    // func-net inner dim (padded to 16 in registers)
constexpr int OUTD = 8;     // output dim

typedef float v2f __attribute__((ext_vector_type(2)));

__device__ __forceinline__ float fexp2(float x) {
#if __has_builtin(__builtin_amdgcn_exp2f)
  return __builtin_amdgcn_exp2f(x);
#else
  return exp2f(x);
#endif
}
__device__ __forceinline__ float frcp(float x) {
#if __has_builtin(__builtin_amdgcn_rcpf)
  return __builtin_amdgcn_rcpf(x);
#else
  return 1.0f / x;
#endif
}

// row_ror:K within the 16-lane DPP row; K must be a compile-time constant.
template <int K>
__device__ __forceinline__ float rotk(float x) {
  if constexpr (K == 0) {
    return x;
  } else {
    return __int_as_float(
        __builtin_amdgcn_mov_dpp(__float_as_int(x), 0x120 + K, 0xF, 0xF, true));
  }
}

// v_pk_fma_f32: d = a*b + c elementwise on float2 (full-rate packed fp32).
__device__ __forceinline__ v2f pkfma(v2f a, v2f b, v2f c) {
  return __builtin_elementwise_fma(a, b, c);
}

#define PIN(x) asm volatile("" : "+v"(x))

#define REP16(M) M(0) M(1) M(2) M(3) M(4) M(5) M(6) M(7) \
                 M(8) M(9) M(10) M(11) M(12) M(13) M(14) M(15)
#define REP8(M) M(0) M(1) M(2) M(3) M(4) M(5) M(6) M(7)

// 16 lanes per batch row. 4096*16 = 65536 threads = 1024 waves = 1 wave/SIMD.
// amdgpu_waves_per_eu(1,1): the grid only ever achieves 1 wave/SIMD, so give
// the register allocator the full 512-VGPR budget. The previous version's
// __launch_bounds__(256,1) did NOT achieve this (VGPR_Count=92 with ~138 live
// pinned values -> ~46 regs spilled to scratch, reloaded every iteration).
__global__ __launch_bounds__(256)
__attribute__((amdgpu_waves_per_eu(1, 1)))
void node_kernel(
    const float* __restrict__ times, const float* __restrict__ initial,
    const float* __restrict__ Wi, const float* __restrict__ bi,
    const float* __restrict__ Wf0, const float* __restrict__ bf0,
    const float* __restrict__ Wf1, const float* __restrict__ bf1,
    const float* __restrict__ Wf2, const float* __restrict__ bf2,
    const float* __restrict__ Wf3, const float* __restrict__ bf3,
    const float* __restrict__ Wl, const float* __restrict__ bl,
    float* __restrict__ out) {
  const int tid = blockIdx.x * 256 + threadIdx.x;
  const int row = tid >> 4;   // batch row, 0..4095
  const int q   = tid & 15;   // position within the 16-lane ring

  // DPP direction probe: correct under either hardware rotate convention.
  int s1 = __builtin_amdgcn_mov_dpp(q, 0x121, 0xF, 0xF, true);
  const int dir = (s1 == ((q + 1) & 15)) ? 1 : -1;

  const bool qv = (q < HH);

  // ---- activation algebra absorption ----
  // tanh(a) = 1 - 2*r with r = 1/(exp2(a*CS)+1), CS = 2*log2(e).
  // Fold CS into the producing layer's (W,b); fold the affine (1-2r) into the
  // consuming layer:  W_cons' = -2*W_cons (*CS if its output feeds a tanh),
  //                   b_cons' = b_cons + colsum(W_cons)  (*CS likewise).
  // Per activation this leaves just {exp2, add 1, rcp} on the critical path.
  const float CS = 2.8853900817779268f;

  float cs1 = 0.f, cs2 = 0.f;
  if (qv) {
#pragma unroll
    for (int e = 0; e < HH; ++e) {
      cs1 += Wf1[e * HH + q];
      cs2 += Wf2[e * HH + q];
    }
  }
  float cs30 = 0.f, cs31 = 0.f;
#pragma unroll
  for (int e = 0; e < HH; ++e) {
    cs30 += Wf3[e * HID + 2 * q + 0];
    cs31 += Wf3[e * HID + 2 * q + 1];
  }

  // Bias seeds as v2f so accumulator chains start at a pk_fma (no zero-init movs).
  v2f b0p = {qv ? bf0[q] * CS : 0.f, 0.f};
  v2f b1p = {qv ? (bf1[q] + cs1) * CS : 0.f, 0.f};
  v2f b2p = {qv ? (bf2[q] + cs2) * CS : 0.f, 0.f};
  v2f b3p = {bf3[2 * q + 0] + cs30, bf3[2 * q + 1] + cs31};
  v2f blp = {bl[q & 7], 0.f};
  PIN(b0p); PIN(b1p); PIN(b2p); PIN(b3p); PIN(blp);

  // --- weight registers as float2 pairs, pre-rotated into ring order ---
  // wp0_k = CS  * (Wf0[2p][q], Wf0[2p+1][q])      pairs with rotated (h0,h1)
  // wlp_k =       (Wl[2p][q&7], Wl[2p+1][q&7])    same pairing (shares rotations)
  // wp3_k = -2  * (Wf3[p][2q], Wf3[p][2q+1])      splat-r2 times component pair
  // wp1_j/wp2_j = -2*CS * (w[p(2j)][q], w[p(2j+1)][q]) consecutive rotations
#define DECLK(k) v2f wp0_##k, wlp_##k, wp3_##k;
  REP16(DECLK)
#undef DECLK
#define DECLJ(j) v2f wp1_##j, wp2_##j;
  REP8(DECLJ)
#undef DECLJ

#define INITK(k)                                                        \
  {                                                                     \
    int p = (q + dir * (k)) & 15;                                       \
    bool pv = (p < HH);                                                 \
    wp0_##k = (v2f){qv ? CS * Wf0[(2 * p + 0) * HH + q] : 0.f,          \
                    qv ? CS * Wf0[(2 * p + 1) * HH + q] : 0.f};         \
    wlp_##k = (v2f){Wl[(2 * p + 0) * OUTD + (q & 7)],                   \
                    Wl[(2 * p + 1) * OUTD + (q & 7)]};                  \
    wp3_##k = (v2f){pv ? -2.f * Wf3[p * HID + 2 * q + 0] : 0.f,         \
                    pv ? -2.f * Wf3[p * HID + 2 * q + 1] : 0.f};        \
    PIN(wp0_##k); PIN(wlp_##k); PIN(wp3_##k);                           \
  }
  REP16(INITK)
#undef INITK

#define INITJ(j)                                                          \
  {                                                                       \
    int p0 = (q + dir * (2 * (j) + 0)) & 15;                              \
    int p1 = (q + dir * (2 * (j) + 1)) & 15;                              \
    wp1_##j = (v2f){(p0 < HH && qv) ? -2.f * CS * Wf1[p0 * HH + q] : 0.f, \
                    (p1 < HH && qv) ? -2.f * CS * Wf1[p1 * HH + q] : 0.f};\
    wp2_##j = (v2f){(p0 < HH && qv) ? -2.f * CS * Wf2[p0 * HH + q] : 0.f, \
                    (p1 < HH && qv) ? -2.f * CS * Wf2[p1 * HH + q] : 0.f};\
    PIN(wp1_##j); PIN(wp2_##j);                                           \
  }
  REP8(INITJ)
#undef INITJ

  // --- h0 = initial @ Wi + bi ; this lane owns components 2q, 2q+1 (true h,
  // unscaled: the output projection consumes it directly).
  float h0 = bi[2 * q + 0];
  float h1 = bi[2 * q + 1];
  {
    const float* ini = initial + (size_t)row * 16;
#pragma unroll
    for (int i = 0; i < 16; ++i) {
      float x = ini[i];
      h0 = fmaf(x, Wi[i * HID + 2 * q + 0], h0);
      h1 = fmaf(x, Wi[i * HID + 2 * q + 1], h1);
    }
  }

  // 32-bit element offset: max 4096*8000 + 7 < 2^25, fits easily.
  unsigned ooff = (unsigned)row * (unsigned)(TN * OUTD) + (unsigned)(q & 7);
  const bool do_store = (q < OUTD);

  // 2-deep uniform times[] pipeline (SMEM): tn1 holds times[t+1], tn2 prefetches
  // times[t+2]; the dt subtract happens at the BOTTOM of the body so the load
  // latency is never on the critical path.
  float tprev = times[0];
  float tn1 = times[1];

#pragma unroll 1
  for (int t = 0; t < TN; ++t) {
    float tn2 = times[(t + 2 < TN) ? (t + 2) : (TN - 1)];

    // --- layer0 (pre-activation a0) + fused output projection, sharing the h
    // rotations. 2 packed chains each, alternating k (dep distance >= 8).
    v2f zA, zB, oA, oB;
#define LP0(k)                                                 \
  {                                                            \
    float hk0 = rotk<k>(h0);                                   \
    float hk1 = rotk<k>(h1);                                   \
    v2f hk = {hk0, hk1};                                       \
    if constexpr ((k) == 0) {                                  \
      zA = pkfma(hk, wp0_0, b0p);                              \
      oA = pkfma(hk, wlp_0, blp);                              \
    } else if constexpr ((k) == 1) {                           \
      zB = hk * wp0_1;                                         \
      oB = hk * wlp_1;                                         \
    } else if constexpr (((k) & 1) == 0) {                     \
      zA = pkfma(hk, wp0_##k, zA);                             \
      oA = pkfma(hk, wlp_##k, oA);                             \
    } else {                                                   \
      zB = pkfma(hk, wp0_##k, zB);                             \
      oB = pkfma(hk, wlp_##k, oB);                             \
    }                                                          \
  }
    REP16(LP0)
#undef LP0
    float a0 = (zA.x + zA.y) + (zB.x + zB.y);
    float r0 = frcp(fexp2(a0) + 1.0f);   // z0 = 1 - 2*r0 (absorbed downstream)

    // o-finish + store issue under the r0 transcendental chain.
    float ov = (oA.x + oA.y) + (oB.x + oB.y);
    if (do_store) out[ooff] = ov;
    ooff += OUTD;

    // --- layer1: pair consecutive rotations (2j, 2j+1), 2 packed chains
    v2f a1A, a1B;
#define LP1(j)                                                     \
  {                                                                \
    float e0 = rotk<2 * (j) + 0>(r0);                              \
    float e1 = rotk<2 * (j) + 1>(r0);                              \
    v2f e = {e0, e1};                                              \
    if constexpr ((j) == 0)      a1A = pkfma(e, wp1_0, b1p);       \
    else if constexpr ((j) == 1) a1B = e * wp1_1;                  \
    else if constexpr (((j) & 1) == 0) a1A = pkfma(e, wp1_##j, a1A);\
    else                               a1B = pkfma(e, wp1_##j, a1B);\
  }
    REP8(LP1)
#undef LP1
    float a1 = (a1A.x + a1A.y) + (a1B.x + a1B.y);
    float r1 = frcp(fexp2(a1) + 1.0f);

    // --- layer2
    v2f a2A, a2B;
#define LP2(j)                                                     \
  {                                                                \
    float e0 = rotk<2 * (j) + 0>(r1);                              \
    float e1 = rotk<2 * (j) + 1>(r1);                              \
    v2f e = {e0, e1};                                              \
    if constexpr ((j) == 0)      a2A = pkfma(e, wp2_0, b2p);       \
    else if constexpr ((j) == 1) a2B = e * wp2_1;                  \
    else if constexpr (((j) & 1) == 0) a2A = pkfma(e, wp2_##j, a2A);\
    else                               a2B = pkfma(e, wp2_##j, a2B);\
  }
    REP8(LP2)
#undef LP2
    float a2 = (a2A.x + a2A.y) + (a2B.x + a2B.y);
    float r2 = frcp(fexp2(a2) + 1.0f);

    // --- layer3: splat r2 * (w3a, w3b) pair into packed (y0, y1) accumulators
    v2f yA, yB;
#define LP3(k)                                                     \
  {                                                                \
    float zk = rotk<k>(r2);                                        \
    v2f zz = {zk, zk};                                             \
    if constexpr ((k) == 0)      yA = pkfma(zz, wp3_0, b3p);       \
    else if constexpr ((k) == 1) yB = zz * wp3_1;                  \
    else if constexpr (((k) & 1) == 0) yA = pkfma(zz, wp3_##k, yA);\
    else                               yB = pkfma(zz, wp3_##k, yB);\
  }
    REP16(LP3)
#undef LP3
    v2f s = yA + yB;
    float dtv = tn1 - tprev;   // == 0 at t == TN-1 by construction
    tprev = tn1;
    tn1 = tn2;
    h0 = fmaf(dtv, s.x, h0);
    h1 = fmaf(dtv, s.y, h1);
  }
}

extern "C" void kernel_launch(void* const* d_in, const int* in_sizes, int n_in,
                              void* d_out, int out_size, void* d_ws, size_t ws_size,
                              hipStream_t stream) {
  (void)in_sizes; (void)n_in; (void)d_ws; (void)ws_size; (void)out_size;
  const float* times   = (const float*)d_in[0];
  const float* initial = (const float*)d_in[1];
  const float* Wi  = (const float*)d_in[2];
  const float* bi  = (const float*)d_in[3];
  const float* Wf0 = (const float*)d_in[4];
  const float* bf0 = (const float*)d_in[5];
  const float* Wf1 = (const float*)d_in[6];
  const float* bf1 = (const float*)d_in[7];
  const float* Wf2 = (const float*)d_in[8];
  const float* bf2 = (const float*)d_in[9];
  const float* Wf3 = (const float*)d_in[10];
  const float* bf3 = (const float*)d_in[11];
  const float* Wl  = (const float*)d_in[12];
  const float* bl  = (const float*)d_in[13];

  dim3 grid((BN * 16) / 256);  // 256 blocks -> 1 block/CU, 1 wave/SIMD
  dim3 block(256);
  hipLaunchKernelGGL(node_kernel, grid, block, 0, stream,
                     times, initial, Wi, bi, Wf0, bf0, Wf1, bf1,
                     Wf2, bf2, Wf3, bf3, Wl, bl, (float*)d_out);
}

// Round 2
// 611.298 us; speedup vs baseline: 1.0707x; 1.0050x over previous
//
#include <hip/hip_runtime.h>

#ifndef __has_builtin
#define __has_builtin(x) 0
#endif

// Problem constants (fixed by the reference):
constexpr int TN   = 1000;  // T
constexpr int BN   = 4096;  // B
constexpr int HID  = 32;    // hidden dim
constexpr int HH   = 15;    // func-net inner dim (padded to 16 in registers)
constexpr int OUTD = 8;     // output dim

typedef float v2f __attribute__((ext_vector_type(2)));

__device__ __forceinline__ float fexp2(float x) {
#if __has_builtin(__builtin_amdgcn_exp2f)
  return __builtin_amdgcn_exp2f(x);
#else
  return exp2f(x);
#endif
}
__device__ __forceinline__ float frcp(float x) {
#if __has_builtin(__builtin_amdgcn_rcpf)
  return __builtin_amdgcn_rcpf(x);
#else
  return 1.0f / x;
#endif
}

// row_ror:K within the 16-lane DPP row; K must be a compile-time constant.
template <int K>
__device__ __forceinline__ float rotk(float x) {
  if constexpr (K == 0) {
    return x;
  } else {
    return __int_as_float(
        __builtin_amdgcn_mov_dpp(__float_as_int(x), 0x120 + K, 0xF, 0xF, true));
  }
}

// Force real packed fp32 math: v_pk_fma_f32 / v_pk_mul_f32 (VOP3P, full rate).
// Round-1 counters implied ~380 VALU instr/step vs ~170 intended -> the
// builtin path was scalarizing / inserting pair-building movs. Inline asm
// makes the pairing a hard constraint the RA must coalesce into.
__device__ __forceinline__ v2f pkfma(v2f a, v2f b, v2f c) {
  v2f d;
  asm("v_pk_fma_f32 %0, %1, %2, %3" : "=v"(d) : "v"(a), "v"(b), "v"(c));
  return d;
}
__device__ __forceinline__ v2f pkmul(v2f a, v2f b) {
  v2f d;
  asm("v_pk_mul_f32 %0, %1, %2" : "=v"(d) : "v"(a), "v"(b));
  return d;
}

#define PIN(x) asm volatile("" : "+v"(x))

#define REP16(M) M(0) M(1) M(2) M(3) M(4) M(5) M(6) M(7) \
                 M(8) M(9) M(10) M(11) M(12) M(13) M(14) M(15)
#define REP8(M) M(0) M(1) M(2) M(3) M(4) M(5) M(6) M(7)

// 16 lanes per batch row. 4096*16 = 65536 threads = 1024 waves = 1 wave/SIMD.
__global__ __launch_bounds__(256)
__attribute__((amdgpu_waves_per_eu(1, 1)))
void node_kernel(
    const float* __restrict__ times, const float* __restrict__ initial,
    const float* __restrict__ Wi, const float* __restrict__ bi,
    const float* __restrict__ Wf0, const float* __restrict__ bf0,
    const float* __restrict__ Wf1, const float* __restrict__ bf1,
    const float* __restrict__ Wf2, const float* __restrict__ bf2,
    const float* __restrict__ Wf3, const float* __restrict__ bf3,
    const float* __restrict__ Wl, const float* __restrict__ bl,
    float* __restrict__ out) {
  const int tid = blockIdx.x * 256 + threadIdx.x;
  const int row = tid >> 4;   // batch row, 0..4095
  const int q   = tid & 15;   // position within the 16-lane ring
  const int c   = q & 7;      // owned output column

  // DPP direction probe: correct under either hardware rotate convention.
  int s1 = __builtin_amdgcn_mov_dpp(q, 0x121, 0xF, 0xF, true);
  const int dir = (s1 == ((q + 1) & 15)) ? 1 : -1;

  const bool qv = (q < HH);

  // ---- activation algebra absorption ----
  // tanh(a) = 1 - 2*r with r = 1/(exp2(a*CS)+1), CS = 2*log2(e).
  // Producing layer gets *CS; consuming layer gets W' = -2*W (*CS if it feeds
  // a tanh), b' = b + colsum(W) (*CS likewise).
  const float CS = 2.8853900817779268f;

  float cs1 = 0.f, cs2 = 0.f;
  if (qv) {
#pragma unroll
    for (int e = 0; e < HH; ++e) {
      cs1 += Wf1[e * HH + q];
      cs2 += Wf2[e * HH + q];
    }
  }
  float cs30 = 0.f, cs31 = 0.f;
#pragma unroll
  for (int e = 0; e < HH; ++e) {
    cs30 += Wf3[e * HID + 2 * q + 0];
    cs31 += Wf3[e * HID + 2 * q + 1];
  }

  // h-update bias (scalar; folded into h at loop top, off critical path):
  // h' = h + dt*(b3 + sum_p r2[p] * (-2*Wf3[p][comp]))
  float b30 = bf3[2 * q + 0] + cs30;
  float b31 = bf3[2 * q + 1] + cs31;

  // o-recurrence bias: boy[c] = sum_e (colsum_p Wf3[p][e] + bf3[e]) * Wl[e][c]
  float boy = 0.f;
#pragma unroll 4
  for (int e = 0; e < HID; ++e) {
    float colp = bf3[e];
#pragma unroll
    for (int p = 0; p < HH; ++p) colp += Wf3[p * HID + e];
    boy = fmaf(colp, Wl[e * OUTD + c], boy);
  }

  // tanh-layer bias seeds (v2f so chain A starts at a pk_fma).
  v2f b0p = {qv ? bf0[q] * CS : 0.f, 0.f};
  v2f b1p = {qv ? (bf1[q] + cs1) * CS : 0.f, 0.f};
  v2f b2p = {qv ? (bf2[q] + cs2) * CS : 0.f, 0.f};
  PIN(b0p); PIN(b1p); PIN(b2p);

  // --- weight registers (all v2f pairs, pre-rotated into ring order) ---
  // wp0_k  = CS * (Wf0[2p(k)][q], Wf0[2p(k)+1][q])    pairs with (h0,h1) rot k
  // wp1_j / wp2_j = -2CS * (W[p(2j)][q], W[p(2j+1)][q])   k-paired
  // w3A_m  = -2 * (Wf3[p(2m)][2q],   Wf3[p(2m+1)][2q])    k-paired, col 2q
  // w3B_m  = -2 * (Wf3[p(2m)][2q+1], Wf3[p(2m+1)][2q+1])  k-paired, col 2q+1
  // w3l_m  = -2 * ((Wf3@Wl)[p(2m)][c], (Wf3@Wl)[p(2m+1)][c])  o-recurrence
#define DECLK(k) v2f wp0_##k;
  REP16(DECLK)
#undef DECLK
#define DECLJ(j) v2f wp1_##j, wp2_##j, w3A_##j, w3B_##j, w3l_##j;
  REP8(DECLJ)
#undef DECLJ

#define INITK(k)                                                        \
  {                                                                     \
    int p = (q + dir * (k)) & 15;                                       \
    wp0_##k = (v2f){qv ? CS * Wf0[(2 * p + 0) * HH + q] : 0.f,          \
                    qv ? CS * Wf0[(2 * p + 1) * HH + q] : 0.f};         \
    PIN(wp0_##k);                                                       \
  }
  REP16(INITK)
#undef INITK

#define INITJ(j)                                                          \
  {                                                                       \
    int p0 = (q + dir * (2 * (j) + 0)) & 15;                              \
    int p1 = (q + dir * (2 * (j) + 1)) & 15;                              \
    bool v0 = (p0 < HH) && qv, v1 = (p1 < HH) && qv;                      \
    wp1_##j = (v2f){v0 ? -2.f * CS * Wf1[p0 * HH + q] : 0.f,              \
                    v1 ? -2.f * CS * Wf1[p1 * HH + q] : 0.f};             \
    wp2_##j = (v2f){v0 ? -2.f * CS * Wf2[p0 * HH + q] : 0.f,              \
                    v1 ? -2.f * CS * Wf2[p1 * HH + q] : 0.f};             \
    PIN(wp1_##j); PIN(wp2_##j);                                           \
  }
  REP8(INITJ)
#undef INITJ

#define INIT3(m)                                                          \
  {                                                                       \
    int p0 = (q + dir * (2 * (m) + 0)) & 15;                              \
    int p1 = (q + dir * (2 * (m) + 1)) & 15;                              \
    bool v0 = (p0 < HH), v1 = (p1 < HH);                                  \
    w3A_##m = (v2f){v0 ? -2.f * Wf3[p0 * HID + 2 * q + 0] : 0.f,          \
                    v1 ? -2.f * Wf3[p1 * HID + 2 * q + 0] : 0.f};         \
    w3B_##m = (v2f){v0 ? -2.f * Wf3[p0 * HID + 2 * q + 1] : 0.f,          \
                    v1 ? -2.f * Wf3[p1 * HID + 2 * q + 1] : 0.f};         \
    float d0 = 0.f, d1 = 0.f;                                             \
    if (v0) {                                                             \
      _Pragma("unroll 4") for (int e = 0; e < HID; ++e)                   \
          d0 = fmaf(Wf3[p0 * HID + e], Wl[e * OUTD + c], d0);             \
    }                                                                     \
    if (v1) {                                                             \
      _Pragma("unroll 4") for (int e = 0; e < HID; ++e)                   \
          d1 = fmaf(Wf3[p1 * HID + e], Wl[e * OUTD + c], d1);             \
    }                                                                     \
    w3l_##m = (v2f){-2.f * d0, -2.f * d1};                                \
    PIN(w3A_##m); PIN(w3B_##m); PIN(w3l_##m);                             \
  }
  REP8(INIT3)
#undef INIT3

  // --- h0 = initial @ Wi + bi ; this lane owns components 2q, 2q+1
  float h0 = bi[2 * q + 0];
  float h1 = bi[2 * q + 1];
  {
    const float* ini = initial + (size_t)row * 16;
#pragma unroll
    for (int i = 0; i < 16; ++i) {
      float x = ini[i];
      h0 = fmaf(x, Wi[i * HID + 2 * q + 0], h0);
      h1 = fmaf(x, Wi[i * HID + 2 * q + 1], h1);
    }
  }

  // --- o(0) = h(0) @ Wl + bl, via the same rotation ring (one-time).
  float o = bl[c];
#define O0K(k)                                                  \
  {                                                             \
    float a_ = rotk<k>(h0);                                     \
    float b_ = rotk<k>(h1);                                     \
    int p = (q + dir * (k)) & 15;                               \
    o = fmaf(a_, Wl[(2 * p + 0) * OUTD + c], o);                \
    o = fmaf(b_, Wl[(2 * p + 1) * OUTD + c], o);                \
  }
  REP16(O0K)
#undef O0K

  // byte offset for the store; global_store saddr + 32-bit voffset form.
  unsigned obyte = ((unsigned)row * (unsigned)(TN * OUTD) + (unsigned)c) * 4u;
  char* outb = (char*)out;
  const bool do_store = (q < OUTD);

  // 2-deep uniform times[] pipeline (scalar loads).
  float tprev = times[0];
  float tn1 = times[1];

#pragma unroll 1
  for (int t = 0; t < TN; ++t) {
    float tn2 = times[(t + 2 < TN) ? (t + 2) : (TN - 1)];
    float dtv = tn1 - tprev;   // == 0 at t == TN-1 by construction
    tprev = tn1;
    tn1 = tn2;

    // store o(t): fully independent of this step's compute -> latency hidden
    if (do_store) *(float*)(outb + obyte) = o;
    obyte += OUTD * 4;

    // bias parts of the updates, off the critical path (inputs ready now)
    float h0b = fmaf(dtv, b30, h0);
    float h1b = fmaf(dtv, b31, h1);
    float ob  = fmaf(dtv, boy, o);

    // --- layer0: a0 = CS*(h @ Wf0 + bf0)[q]; 2 packed chains, alternating k
    v2f zA, zB;
#define LP0(k)                                                 \
  {                                                            \
    float hk0 = rotk<k>(h0);                                   \
    float hk1 = rotk<k>(h1);                                   \
    v2f hk = {hk0, hk1};                                       \
    if constexpr ((k) == 0)      zA = pkfma(hk, wp0_0, b0p);   \
    else if constexpr ((k) == 1) zB = pkmul(hk, wp0_1);        \
    else if constexpr (((k) & 1) == 0) zA = pkfma(hk, wp0_##k, zA); \
    else                               zB = pkfma(hk, wp0_##k, zB); \
  }
    REP16(LP0)
#undef LP0
    float a0 = (zA.x + zA.y) + (zB.x + zB.y);
    float r0 = frcp(fexp2(a0) + 1.0f);   // z0 = 1 - 2*r0 (absorbed downstream)

    // --- layer1: k-paired rotations of r0
    v2f a1A, a1B;
#define LP1(j)                                                     \
  {                                                                \
    float e0 = rotk<2 * (j) + 0>(r0);                              \
    float e1 = rotk<2 * (j) + 1>(r0);                              \
    v2f e = {e0, e1};                                              \
    if constexpr ((j) == 0)      a1A = pkfma(e, wp1_0, b1p);       \
    else if constexpr ((j) == 1) a1B = pkmul(e, wp1_1);            \
    else if constexpr (((j) & 1) == 0) a1A = pkfma(e, wp1_##j, a1A);\
    else                               a1B = pkfma(e, wp1_##j, a1B);\
  }
    REP8(LP1)
#undef LP1
    float a1 = (a1A.x + a1A.y) + (a1B.x + a1B.y);
    float r1 = frcp(fexp2(a1) + 1.0f);

    // --- layer2
    v2f a2A, a2B;
#define LP2(j)                                                     \
  {                                                                \
    float e0 = rotk<2 * (j) + 0>(r1);                              \
    float e1 = rotk<2 * (j) + 1>(r1);                              \
    v2f e = {e0, e1};                                              \
    if constexpr ((j) == 0)      a2A = pkfma(e, wp2_0, b2p);       \
    else if constexpr ((j) == 1) a2B = pkmul(e, wp2_1);            \
    else if constexpr (((j) & 1) == 0) a2A = pkfma(e, wp2_##j, a2A);\
    else                               a2B = pkfma(e, wp2_##j, a2B);\
  }
    REP8(LP2)
#undef LP2
    float a2 = (a2A.x + a2A.y) + (a2B.x + a2B.y);
    float r2 = frcp(fexp2(a2) + 1.0f);

    // --- layer3 + o-delta: k-paired rotations of r2 feed three packed chains
    //   acc0 -> h component 2q,  acc1 -> 2q+1,  oyc -> o column c
    v2f acc0, acc1, oyc;
#define LP3(m)                                                     \
  {                                                                \
    float e0 = rotk<2 * (m) + 0>(r2);                              \
    float e1 = rotk<2 * (m) + 1>(r2);                              \
    v2f e = {e0, e1};                                              \
    if constexpr ((m) == 0) {                                      \
      acc0 = pkmul(e, w3A_0);                                      \
      acc1 = pkmul(e, w3B_0);                                      \
      oyc  = pkmul(e, w3l_0);                                      \
    } else {                                                       \
      acc0 = pkfma(e, w3A_##m, acc0);                              \
      acc1 = pkfma(e, w3B_##m, acc1);                              \
      oyc  = pkfma(e, w3l_##m, oyc);                               \
    }                                                              \
  }
    REP8(LP3)
#undef LP3

    h0 = fmaf(dtv, acc0.x + acc0.y, h0b);
    h1 = fmaf(dtv, acc1.x + acc1.y, h1b);
    o  = fmaf(dtv, oyc.x + oyc.y,  ob);
  }
}

extern "C" void kernel_launch(void* const* d_in, const int* in_sizes, int n_in,
                              void* d_out, int out_size, void* d_ws, size_t ws_size,
                              hipStream_t stream) {
  (void)in_sizes; (void)n_in; (void)d_ws; (void)ws_size; (void)out_size;
  const float* times   = (const float*)d_in[0];
  const float* initial = (const float*)d_in[1];
  const float* Wi  = (const float*)d_in[2];
  const float* bi  = (const float*)d_in[3];
  const float* Wf0 = (const float*)d_in[4];
  const float* bf0 = (const float*)d_in[5];
  const float* Wf1 = (const float*)d_in[6];
  const float* bf1 = (const float*)d_in[7];
  const float* Wf2 = (const float*)d_in[8];
  const float* bf2 = (const float*)d_in[9];
  const float* Wf3 = (const float*)d_in[10];
  const float* bf3 = (const float*)d_in[11];
  const float* Wl  = (const float*)d_in[12];
  const float* bl  = (const float*)d_in[13];

  dim3 grid((BN * 16) / 256);  // 256 blocks -> 1 block/CU, 1 wave/SIMD
  dim3 block(256);
  hipLaunchKernelGGL(node_kernel, grid, block, 0, stream,
                     times, initial, Wi, bi, Wf0, bf0, Wf1, bf1,
                     Wf2, bf2, Wf3, bf3, Wl, bl, (float*)d_out);
}

// Round 4
// 528.189 us; speedup vs baseline: 1.2392x; 1.1573x over previous
//
#include <hip/hip_runtime.h>

#ifndef __has_builtin
#define __has_builtin(x) 0
#endif

// Problem constants (fixed by the reference):
constexpr int TN   = 1000;  // T
constexpr int BN   = 4096;  // B
constexpr int HID  = 32;    // hidden dim
constexpr int HH   = 15;    // func-net inner dim (padded to 16 in registers)
constexpr int OUTD = 8;     // output dim

__device__ __forceinline__ float fexp2(float x) {
#if __has_builtin(__builtin_amdgcn_exp2f)
  return __builtin_amdgcn_exp2f(x);
#else
  return exp2f(x);
#endif
}
__device__ __forceinline__ float frcp(float x) {
#if __has_builtin(__builtin_amdgcn_rcpf)
  return __builtin_amdgcn_rcpf(x);
#else
  return 1.0f / x;
#endif
}

// row_ror:K within the 16-lane DPP row, via the INTRINSIC so the compiler's
// DPP hazard recognizer manages wait states (round 3's raw-asm version
// violated the VALU->DPP-read 2-wait-state rule under scheduling and failed).
// Written as mov_dpp feeding src0 of an accumulator-reuse fma, which
// GCNDPPCombine folds into v_fmac_f32_dpp where legal.
template <int K>
__device__ __forceinline__ float rotk(float x) {
  if constexpr (K == 0) {
    return x;
  } else {
    return __int_as_float(
        __builtin_amdgcn_mov_dpp(__float_as_int(x), 0x120 + K, 0xF, 0xF, true));
  }
}

#define PIN(x) asm volatile("" : "+v"(x))

#define REP16(M) M(0) M(1) M(2) M(3) M(4) M(5) M(6) M(7) \
                 M(8) M(9) M(10) M(11) M(12) M(13) M(14) M(15)

// 16 lanes per batch row. 4096*16 = 65536 threads = 1024 waves = 1 wave/SIMD.
__global__ __launch_bounds__(256)
__attribute__((amdgpu_waves_per_eu(1, 1)))
void node_kernel(
    const float* __restrict__ times, const float* __restrict__ initial,
    const float* __restrict__ Wi, const float* __restrict__ bi,
    const float* __restrict__ Wf0, const float* __restrict__ bf0,
    const float* __restrict__ Wf1, const float* __restrict__ bf1,
    const float* __restrict__ Wf2, const float* __restrict__ bf2,
    const float* __restrict__ Wf3, const float* __restrict__ bf3,
    const float* __restrict__ Wl, const float* __restrict__ bl,
    float* __restrict__ out) {
  __shared__ float sdt[TN + 2];   // padded: sdt[TN-1..TN+1] = 0, no clamps

  const int tid = blockIdx.x * 256 + threadIdx.x;
  const int row = tid >> 4;   // batch row, 0..4095
  const int q   = tid & 15;   // position within the 16-lane ring
  const int c   = q & 7;      // owned output column

  // Precompute dt[] into LDS: per-step load is a ds_read (lgkmcnt), decoupled
  // from the store's vmcnt; 1-deep prefetched below.
  for (int i = threadIdx.x; i < TN + 2; i += 256) {
    float d = 0.f;
    if (i < TN - 1) d = times[i + 1] - times[i];
    sdt[i] = d;
  }

  // DPP direction probe: correct under either hardware rotate convention.
  int s1 = __builtin_amdgcn_mov_dpp(q, 0x121, 0xF, 0xF, true);
  const int dir = (s1 == ((q + 1) & 15)) ? 1 : -1;

  const bool qv = (q < HH);

  // ---- activation algebra absorption (identical to round 2, which passed) --
  // tanh(a) = 1 - 2*r with r = 1/(exp2(a*CS)+1), CS = 2*log2(e).
  const float CS = 2.8853900817779268f;

  float cs1 = 0.f, cs2 = 0.f;
  if (qv) {
#pragma unroll
    for (int e = 0; e < HH; ++e) {
      cs1 += Wf1[e * HH + q];
      cs2 += Wf2[e * HH + q];
    }
  }
  float cs30 = 0.f, cs31 = 0.f;
#pragma unroll
  for (int e = 0; e < HH; ++e) {
    cs30 += Wf3[e * HID + 2 * q + 0];
    cs31 += Wf3[e * HID + 2 * q + 1];
  }

  float b30 = bf3[2 * q + 0] + cs30;
  float b31 = bf3[2 * q + 1] + cs31;

  // o-recurrence bias: boy[c] = sum_e (colsum_p Wf3[p][e] + bf3[e]) * Wl[e][c]
  float boy = 0.f;
#pragma unroll 4
  for (int e = 0; e < HID; ++e) {
    float colp = bf3[e];
#pragma unroll
    for (int p = 0; p < HH; ++p) colp += Wf3[p * HID + e];
    boy = fmaf(colp, Wl[e * OUTD + c], boy);
  }

  float b0s = qv ? bf0[q] * CS : 0.f;
  float b1s = qv ? (bf1[q] + cs1) * CS : 0.f;
  float b2s = qv ? (bf2[q] + cs2) * CS : 0.f;
  PIN(b0s); PIN(b1s); PIN(b2s);

  // --- scalar weight registers, pre-rotated into ring order ---
  // w0a_k = CS*Wf0[2p(k)+0][q], w0b_k = CS*Wf0[2p(k)+1][q]
  // w1_k  = -2CS*Wf1[p(k)][q],  w2_k = -2CS*Wf2[p(k)][q]
  // w3a_k = -2*Wf3[p(k)][2q],   w3b_k = -2*Wf3[p(k)][2q+1]
  // w3l_k = -2*(Wf3@Wl)[p(k)][c]   (o-recurrence)
#define DECLW(k) float w0a_##k, w0b_##k, w1_##k, w2_##k, w3a_##k, w3b_##k, w3l_##k;
  REP16(DECLW)
#undef DECLW

#define INITW(k)                                                        \
  {                                                                     \
    int p = (q + dir * (k)) & 15;                                       \
    bool pv = (p < HH);                                                 \
    w0a_##k = qv ? CS * Wf0[(2 * p + 0) * HH + q] : 0.f;                \
    w0b_##k = qv ? CS * Wf0[(2 * p + 1) * HH + q] : 0.f;                \
    w1_##k = (pv && qv) ? -2.f * CS * Wf1[p * HH + q] : 0.f;            \
    w2_##k = (pv && qv) ? -2.f * CS * Wf2[p * HH + q] : 0.f;            \
    w3a_##k = pv ? -2.f * Wf3[p * HID + 2 * q + 0] : 0.f;               \
    w3b_##k = pv ? -2.f * Wf3[p * HID + 2 * q + 1] : 0.f;               \
    float d_ = 0.f;                                                     \
    if (pv) {                                                           \
      _Pragma("unroll 4") for (int e = 0; e < HID; ++e)                 \
          d_ = fmaf(Wf3[p * HID + e], Wl[e * OUTD + c], d_);            \
    }                                                                   \
    w3l_##k = -2.f * d_;                                                \
    PIN(w0a_##k); PIN(w0b_##k); PIN(w1_##k); PIN(w2_##k);               \
    PIN(w3a_##k); PIN(w3b_##k); PIN(w3l_##k);                           \
  }
  REP16(INITW)
#undef INITW

  // --- h0 = initial @ Wi + bi ; this lane owns components 2q, 2q+1
  float h0 = bi[2 * q + 0];
  float h1 = bi[2 * q + 1];
  {
    const float* ini = initial + (size_t)row * 16;
#pragma unroll
    for (int i = 0; i < 16; ++i) {
      float x = ini[i];
      h0 = fmaf(x, Wi[i * HID + 2 * q + 0], h0);
      h1 = fmaf(x, Wi[i * HID + 2 * q + 1], h1);
    }
  }

  // --- o(0) = h(0) @ Wl + bl, via the rotation ring (one-time).
  // Note: o depends on q only through c = q&7 (the k-sum covers all p), so
  // lanes 8..15 duplicate lanes 0..7 -> the per-step store can be
  // unconditional (duplicate lanes write the same value to the same address).
  float o = bl[c];
#define O0K(k)                                                  \
  {                                                             \
    float a_ = rotk<k>(h0);                                     \
    float b_ = rotk<k>(h1);                                     \
    int p = (q + dir * (k)) & 15;                               \
    o = fmaf(a_, Wl[(2 * p + 0) * OUTD + c], o);                \
    o = fmaf(b_, Wl[(2 * p + 1) * OUTD + c], o);                \
  }
  REP16(O0K)
#undef O0K

  unsigned obyte = ((unsigned)row * (unsigned)(TN * OUTD) + (unsigned)c) * 4u;
  char* outb = (char*)out;

  __syncthreads();
  float dv = sdt[0];
  float dn = sdt[1];

#pragma unroll 1
  for (int t = 0; t < TN; ++t) {
    float dnn = sdt[t + 2];   // padded table: no clamp

    // store o(t): value finalized last iteration -> latency fully hidden
    *(float*)(outb + obyte) = o;
    obyte += OUTD * 4;

    float dtv = dv;
    float h0b = fmaf(dtv, b30, h0);
    float h1b = fmaf(dtv, b31, h1);
    float ob  = fmaf(dtv, boy, o);

    // --- layer0: a0 = CS*(h @ Wf0 + bf0)[q]; 4 chains, fmac-foldable form
    float z_a = fmaf(h0, w0a_0, b0s);
    float z_b = h1 * w0b_0;
    float z_c = rotk<1>(h0) * w0a_1;
    float z_d = rotk<1>(h1) * w0b_1;
#define L0K(k, cA, cB)                      \
    cA = fmaf(rotk<k>(h0), w0a_##k, cA);    \
    cB = fmaf(rotk<k>(h1), w0b_##k, cB);
    L0K(2, z_a, z_b)  L0K(3, z_c, z_d)
    L0K(4, z_a, z_b)  L0K(5, z_c, z_d)
    L0K(6, z_a, z_b)  L0K(7, z_c, z_d)
    L0K(8, z_a, z_b)  L0K(9, z_c, z_d)
    L0K(10, z_a, z_b) L0K(11, z_c, z_d)
    L0K(12, z_a, z_b) L0K(13, z_c, z_d)
    L0K(14, z_a, z_b) L0K(15, z_c, z_d)
#undef L0K
    float a0 = (z_a + z_b) + (z_c + z_d);
    float r0 = frcp(fexp2(a0) + 1.0f);   // z0 = 1 - 2*r0 (absorbed downstream)

    // --- layer1: 4 chains over 16 rotations of r0
    float s_a = fmaf(r0, w1_0, b1s);
    float s_b = rotk<1>(r0) * w1_1;
    float s_c = rotk<2>(r0) * w1_2;
    float s_d = rotk<3>(r0) * w1_3;
#define L1K(k, acc) acc = fmaf(rotk<k>(r0), w1_##k, acc);
    L1K(4, s_a)  L1K(5, s_b)  L1K(6, s_c)  L1K(7, s_d)
    L1K(8, s_a)  L1K(9, s_b)  L1K(10, s_c) L1K(11, s_d)
    L1K(12, s_a) L1K(13, s_b) L1K(14, s_c) L1K(15, s_d)
#undef L1K
    float a1 = (s_a + s_b) + (s_c + s_d);
    float r1 = frcp(fexp2(a1) + 1.0f);

    // --- layer2
    float u_a = fmaf(r1, w2_0, b2s);
    float u_b = rotk<1>(r1) * w2_1;
    float u_c = rotk<2>(r1) * w2_2;
    float u_d = rotk<3>(r1) * w2_3;
#define L2K(k, acc) acc = fmaf(rotk<k>(r1), w2_##k, acc);
    L2K(4, u_a)  L2K(5, u_b)  L2K(6, u_c)  L2K(7, u_d)
    L2K(8, u_a)  L2K(9, u_b)  L2K(10, u_c) L2K(11, u_d)
    L2K(12, u_a) L2K(13, u_b) L2K(14, u_c) L2K(15, u_d)
#undef L2K
    float a2 = (u_a + u_b) + (u_c + u_d);
    float r2 = frcp(fexp2(a2) + 1.0f);

    // --- layer3 + o-delta: one rotation feeds three chains (h-comp0,
    // h-comp1, o-col). 6 accumulators -> dep distance 6.
    float yP = r2 * w3a_0;
    float yR = r2 * w3b_0;
    float yU = r2 * w3l_0;
    float e1_ = rotk<1>(r2);
    float yQ = e1_ * w3a_1;
    float yS = e1_ * w3b_1;
    float yV = e1_ * w3l_1;
#define L3K(k, cH0, cH1, cO)             \
    {                                    \
      float e_ = rotk<k>(r2);            \
      cH0 = fmaf(e_, w3a_##k, cH0);      \
      cH1 = fmaf(e_, w3b_##k, cH1);      \
      cO  = fmaf(e_, w3l_##k, cO);       \
    }
    L3K(2, yP, yR, yU)  L3K(3, yQ, yS, yV)
    L3K(4, yP, yR, yU)  L3K(5, yQ, yS, yV)
    L3K(6, yP, yR, yU)  L3K(7, yQ, yS, yV)
    L3K(8, yP, yR, yU)  L3K(9, yQ, yS, yV)
    L3K(10, yP, yR, yU) L3K(11, yQ, yS, yV)
    L3K(12, yP, yR, yU) L3K(13, yQ, yS, yV)
    L3K(14, yP, yR, yU) L3K(15, yQ, yS, yV)
#undef L3K

    h0 = fmaf(dtv, yP + yQ, h0b);
    h1 = fmaf(dtv, yR + yS, h1b);
    o  = fmaf(dtv, yU + yV, ob);

    dv = dn;
    dn = dnn;
  }
}

extern "C" void kernel_launch(void* const* d_in, const int* in_sizes, int n_in,
                              void* d_out, int out_size, void* d_ws, size_t ws_size,
                              hipStream_t stream) {
  (void)in_sizes; (void)n_in; (void)d_ws; (void)ws_size; (void)out_size;
  const float* times   = (const float*)d_in[0];
  const float* initial = (const float*)d_in[1];
  const float* Wi  = (const float*)d_in[2];
  const float* bi  = (const float*)d_in[3];
  const float* Wf0 = (const float*)d_in[4];
  const float* bf0 = (const float*)d_in[5];
  const float* Wf1 = (const float*)d_in[6];
  const float* bf1 = (const float*)d_in[7];
  const float* Wf2 = (const float*)d_in[8];
  const float* bf2 = (const float*)d_in[9];
  const float* Wf3 = (const float*)d_in[10];
  const float* bf3 = (const float*)d_in[11];
  const float* Wl  = (const float*)d_in[12];
  const float* bl  = (const float*)d_in[13];

  dim3 grid((BN * 16) / 256);  // 256 blocks -> 1 block/CU, 1 wave/SIMD
  dim3 block(256);
  hipLaunchKernelGGL(node_kernel, grid, block, 0, stream,
                     times, initial, Wi, bi, Wf0, bf0, Wf1, bf1,
                     Wf2, bf2, Wf3, bf3, Wl, bl, (float*)d_out);
}

// Round 5
// 504.258 us; speedup vs baseline: 1.2980x; 1.0475x over previous
//
#include <hip/hip_runtime.h>

#ifndef __has_builtin
#define __has_builtin(x) 0
#endif

// Problem constants (fixed by the reference):
constexpr int TN   = 1000;  // T
constexpr int BN   = 4096;  // B
constexpr int HID  = 32;    // hidden dim
constexpr int HH   = 15;    // func-net inner dim (padded to 16 in registers)
constexpr int OUTD = 8;     // output dim

__device__ __forceinline__ float fexp2(float x) {
#if __has_builtin(__builtin_amdgcn_exp2f)
  return __builtin_amdgcn_exp2f(x);
#else
  return exp2f(x);
#endif
}
__device__ __forceinline__ float frcp(float x) {
#if __has_builtin(__builtin_amdgcn_rcpf)
  return __builtin_amdgcn_rcpf(x);
#else
  return 1.0f / x;
#endif
}

// row_ror:K within the 16-lane DPP row (intrinsic form, init-time only).
template <int K>
__device__ __forceinline__ float rotk(float x) {
  if constexpr (K == 0) {
    return x;
  } else {
    return __int_as_float(
        __builtin_amdgcn_mov_dpp(__float_as_int(x), 0x120 + K, 0xF, 0xF, true));
  }
}

// ---- fused rotate+FMA: one v_fmac_f32_dpp per (rotate, mul, acc) ----
// Round-4 counters proved GCNDPPCombine does NOT fold mov_dpp+fma (busy
// cycles identical to round 2), so the ~105 standalone v_mov_dpp/step are
// the largest cost bucket. Round 3 tried raw asm and failed because the
// asms were non-volatile: the scheduler hoisted unguarded DPPs above the
// s_nop-guarded one, violating the VALU-write -> DPP-read 2-wait-state
// rule. This version makes every DPP asm VOLATILE (volatile asms keep
// their mutual program order) and puts an s_nop 1 guard inside the
// textually-first DPP of each layer: worst case the guard sits directly
// after the source's producer (frcp / h-update fma), giving the required
// 2 wait states; anything the compiler inserts only adds margin. No exec
// writes inside the loop (store is unconditional), so the exec->DPP
// hazard cannot arise. Math is byte-identical to the passing round 4.
#define FMAC_DPP(acc, src, w, K)                                            \
  asm volatile("v_fmac_f32_dpp %0, %1, %2 row_ror:" #K                      \
               " row_mask:0xf bank_mask:0xf"                                \
               : "+v"(acc) : "v"(src), "v"(w))

#define MUL_DPP(dst, src, w, K)                                             \
  asm volatile("v_mul_f32_dpp %0, %1, %2 row_ror:" #K                       \
               " row_mask:0xf bank_mask:0xf"                                \
               : "=v"(dst) : "v"(src), "v"(w))

#define MUL_DPP_NOP(dst, src, w, K)                                         \
  asm volatile("s_nop 1\n\t"                                                \
               "v_mul_f32_dpp %0, %1, %2 row_ror:" #K                       \
               " row_mask:0xf bank_mask:0xf"                                \
               : "=v"(dst) : "v"(src), "v"(w))

#define PIN(x) asm volatile("" : "+v"(x))

#define REP16(M) M(0) M(1) M(2) M(3) M(4) M(5) M(6) M(7) \
                 M(8) M(9) M(10) M(11) M(12) M(13) M(14) M(15)

// 16 lanes per batch row. 4096*16 = 65536 threads = 1024 waves = 1 wave/SIMD.
__global__ __launch_bounds__(256)
__attribute__((amdgpu_waves_per_eu(1, 1)))
void node_kernel(
    const float* __restrict__ times, const float* __restrict__ initial,
    const float* __restrict__ Wi, const float* __restrict__ bi,
    const float* __restrict__ Wf0, const float* __restrict__ bf0,
    const float* __restrict__ Wf1, const float* __restrict__ bf1,
    const float* __restrict__ Wf2, const float* __restrict__ bf2,
    const float* __restrict__ Wf3, const float* __restrict__ bf3,
    const float* __restrict__ Wl, const float* __restrict__ bl,
    float* __restrict__ out) {
  __shared__ float sdt[TN + 2];   // padded: sdt[TN-1..TN+1] = 0, no clamps

  const int tid = blockIdx.x * 256 + threadIdx.x;
  const int row = tid >> 4;   // batch row, 0..4095
  const int q   = tid & 15;   // position within the 16-lane ring
  const int c   = q & 7;      // owned output column

  // Precompute dt[] into LDS: per-step load is a ds_read (lgkmcnt), decoupled
  // from the store's vmcnt; 1-deep prefetched below.
  for (int i = threadIdx.x; i < TN + 2; i += 256) {
    float d = 0.f;
    if (i < TN - 1) d = times[i + 1] - times[i];
    sdt[i] = d;
  }

  // DPP direction probe: correct under either hardware rotate convention.
  int s1 = __builtin_amdgcn_mov_dpp(q, 0x121, 0xF, 0xF, true);
  const int dir = (s1 == ((q + 1) & 15)) ? 1 : -1;

  const bool qv = (q < HH);

  // ---- activation algebra absorption (identical to rounds 2/4, passing) ---
  // tanh(a) = 1 - 2*r with r = 1/(exp2(a*CS)+1), CS = 2*log2(e).
  const float CS = 2.8853900817779268f;

  float cs1 = 0.f, cs2 = 0.f;
  if (qv) {
#pragma unroll
    for (int e = 0; e < HH; ++e) {
      cs1 += Wf1[e * HH + q];
      cs2 += Wf2[e * HH + q];
    }
  }
  float cs30 = 0.f, cs31 = 0.f;
#pragma unroll
  for (int e = 0; e < HH; ++e) {
    cs30 += Wf3[e * HID + 2 * q + 0];
    cs31 += Wf3[e * HID + 2 * q + 1];
  }

  float b30 = bf3[2 * q + 0] + cs30;
  float b31 = bf3[2 * q + 1] + cs31;

  // o-recurrence bias: boy[c] = sum_e (colsum_p Wf3[p][e] + bf3[e]) * Wl[e][c]
  float boy = 0.f;
#pragma unroll 4
  for (int e = 0; e < HID; ++e) {
    float colp = bf3[e];
#pragma unroll
    for (int p = 0; p < HH; ++p) colp += Wf3[p * HID + e];
    boy = fmaf(colp, Wl[e * OUTD + c], boy);
  }

  float b0s = qv ? bf0[q] * CS : 0.f;
  float b1s = qv ? (bf1[q] + cs1) * CS : 0.f;
  float b2s = qv ? (bf2[q] + cs2) * CS : 0.f;
  PIN(b0s); PIN(b1s); PIN(b2s);

  // --- scalar weight registers, pre-rotated into ring order ---
  // w0a_k = CS*Wf0[2p(k)+0][q], w0b_k = CS*Wf0[2p(k)+1][q]
  // w1_k  = -2CS*Wf1[p(k)][q],  w2_k = -2CS*Wf2[p(k)][q]
  // w3a_k = -2*Wf3[p(k)][2q],   w3b_k = -2*Wf3[p(k)][2q+1]
  // w3l_k = -2*(Wf3@Wl)[p(k)][c]   (o-recurrence)
#define DECLW(k) float w0a_##k, w0b_##k, w1_##k, w2_##k, w3a_##k, w3b_##k, w3l_##k;
  REP16(DECLW)
#undef DECLW

#define INITW(k)                                                        \
  {                                                                     \
    int p = (q + dir * (k)) & 15;                                       \
    bool pv = (p < HH);                                                 \
    w0a_##k = qv ? CS * Wf0[(2 * p + 0) * HH + q] : 0.f;                \
    w0b_##k = qv ? CS * Wf0[(2 * p + 1) * HH + q] : 0.f;                \
    w1_##k = (pv && qv) ? -2.f * CS * Wf1[p * HH + q] : 0.f;            \
    w2_##k = (pv && qv) ? -2.f * CS * Wf2[p * HH + q] : 0.f;            \
    w3a_##k = pv ? -2.f * Wf3[p * HID + 2 * q + 0] : 0.f;               \
    w3b_##k = pv ? -2.f * Wf3[p * HID + 2 * q + 1] : 0.f;               \
    float d_ = 0.f;                                                     \
    if (pv) {                                                           \
      _Pragma("unroll 4") for (int e = 0; e < HID; ++e)                 \
          d_ = fmaf(Wf3[p * HID + e], Wl[e * OUTD + c], d_);            \
    }                                                                   \
    w3l_##k = -2.f * d_;                                                \
    PIN(w0a_##k); PIN(w0b_##k); PIN(w1_##k); PIN(w2_##k);               \
    PIN(w3a_##k); PIN(w3b_##k); PIN(w3l_##k);                           \
  }
  REP16(INITW)
#undef INITW

  // --- h0 = initial @ Wi + bi ; this lane owns components 2q, 2q+1
  float h0 = bi[2 * q + 0];
  float h1 = bi[2 * q + 1];
  {
    const float* ini = initial + (size_t)row * 16;
#pragma unroll
    for (int i = 0; i < 16; ++i) {
      float x = ini[i];
      h0 = fmaf(x, Wi[i * HID + 2 * q + 0], h0);
      h1 = fmaf(x, Wi[i * HID + 2 * q + 1], h1);
    }
  }

  // --- o(0) = h(0) @ Wl + bl, via the rotation ring (one-time, intrinsics:
  // the compiler's hazard recognizer manages these). o depends on q only
  // through c = q&7, so lanes 8..15 duplicate lanes 0..7 and the per-step
  // store can be unconditional.
  float o = bl[c];
#define O0K(k)                                                  \
  {                                                             \
    float a_ = rotk<k>(h0);                                     \
    float b_ = rotk<k>(h1);                                     \
    int p = (q + dir * (k)) & 15;                               \
    o = fmaf(a_, Wl[(2 * p + 0) * OUTD + c], o);                \
    o = fmaf(b_, Wl[(2 * p + 1) * OUTD + c], o);                \
  }
  REP16(O0K)
#undef O0K

  unsigned obyte = ((unsigned)row * (unsigned)(TN * OUTD) + (unsigned)c) * 4u;
  char* outb = (char*)out;

  __syncthreads();
  float dv = sdt[0];
  float dn = sdt[1];

#pragma unroll 1
  for (int t = 0; t < TN; ++t) {
    float dnn = sdt[t + 2];   // padded table: no clamp

    // store o(t): value finalized last iteration -> latency fully hidden
    *(float*)(outb + obyte) = o;
    obyte += OUTD * 4;

    float dtv = dv;
    float h0b = fmaf(dtv, b30, h0);
    float h1b = fmaf(dtv, b31, h1);
    float ob  = fmaf(dtv, boy, o);

    // --- layer0: a0 = CS*(h @ Wf0 + bf0)[q]; 4 chains, fused fmac_dpp.
    // Guarded first DPP (h0/h1 written by previous iteration's tail fmas).
    float z_a = fmaf(h0, w0a_0, b0s);
    float z_b = h1 * w0b_0;
    float z_c, z_d;
    MUL_DPP_NOP(z_c, h0, w0a_1, 1);
    MUL_DPP(z_d, h1, w0b_1, 1);
#define L0PAIR(k, cA, cB) FMAC_DPP(cA, h0, w0a_##k, k); FMAC_DPP(cB, h1, w0b_##k, k);
    L0PAIR(2, z_a, z_b)  L0PAIR(3, z_c, z_d)
    L0PAIR(4, z_a, z_b)  L0PAIR(5, z_c, z_d)
    L0PAIR(6, z_a, z_b)  L0PAIR(7, z_c, z_d)
    L0PAIR(8, z_a, z_b)  L0PAIR(9, z_c, z_d)
    L0PAIR(10, z_a, z_b) L0PAIR(11, z_c, z_d)
    L0PAIR(12, z_a, z_b) L0PAIR(13, z_c, z_d)
    L0PAIR(14, z_a, z_b) L0PAIR(15, z_c, z_d)
#undef L0PAIR
    float a0 = (z_a + z_b) + (z_c + z_d);
    float r0 = frcp(fexp2(a0) + 1.0f);   // z0 = 1 - 2*r0 (absorbed downstream)

    // --- layer1: 4 chains over 16 rotations of r0 (r0 from frcp -> guard)
    float s_a = fmaf(r0, w1_0, b1s);
    float s_b, s_c, s_d;
    MUL_DPP_NOP(s_b, r0, w1_1, 1);
    MUL_DPP(s_c, r0, w1_2, 2);
    MUL_DPP(s_d, r0, w1_3, 3);
#define L1S(k, acc) FMAC_DPP(acc, r0, w1_##k, k);
    L1S(4, s_a)  L1S(5, s_b)  L1S(6, s_c)  L1S(7, s_d)
    L1S(8, s_a)  L1S(9, s_b)  L1S(10, s_c) L1S(11, s_d)
    L1S(12, s_a) L1S(13, s_b) L1S(14, s_c) L1S(15, s_d)
#undef L1S
    float a1 = (s_a + s_b) + (s_c + s_d);
    float r1 = frcp(fexp2(a1) + 1.0f);

    // --- layer2
    float u_a = fmaf(r1, w2_0, b2s);
    float u_b, u_c, u_d;
    MUL_DPP_NOP(u_b, r1, w2_1, 1);
    MUL_DPP(u_c, r1, w2_2, 2);
    MUL_DPP(u_d, r1, w2_3, 3);
#define L2S(k, acc) FMAC_DPP(acc, r1, w2_##k, k);
    L2S(4, u_a)  L2S(5, u_b)  L2S(6, u_c)  L2S(7, u_d)
    L2S(8, u_a)  L2S(9, u_b)  L2S(10, u_c) L2S(11, u_d)
    L2S(12, u_a) L2S(13, u_b) L2S(14, u_c) L2S(15, u_d)
#undef L2S
    float a2 = (u_a + u_b) + (u_c + u_d);
    float r2 = frcp(fexp2(a2) + 1.0f);

    // --- layer3 + o-delta: 3 targets x 2 chains, dep distance 6
    float yP = r2 * w3a_0;
    float yR = r2 * w3b_0;
    float yU = r2 * w3l_0;
    float yQ, yS, yV;
    MUL_DPP_NOP(yQ, r2, w3a_1, 1);
    MUL_DPP(yS, r2, w3b_1, 1);
    MUL_DPP(yV, r2, w3l_1, 1);
#define L3TRI(k, cH0, cH1, cO)                   \
    FMAC_DPP(cH0, r2, w3a_##k, k);               \
    FMAC_DPP(cH1, r2, w3b_##k, k);               \
    FMAC_DPP(cO,  r2, w3l_##k, k);
    L3TRI(2, yP, yR, yU)  L3TRI(3, yQ, yS, yV)
    L3TRI(4, yP, yR, yU)  L3TRI(5, yQ, yS, yV)
    L3TRI(6, yP, yR, yU)  L3TRI(7, yQ, yS, yV)
    L3TRI(8, yP, yR, yU)  L3TRI(9, yQ, yS, yV)
    L3TRI(10, yP, yR, yU) L3TRI(11, yQ, yS, yV)
    L3TRI(12, yP, yR, yU) L3TRI(13, yQ, yS, yV)
    L3TRI(14, yP, yR, yU) L3TRI(15, yQ, yS, yV)
#undef L3TRI

    h0 = fmaf(dtv, yP + yQ, h0b);
    h1 = fmaf(dtv, yR + yS, h1b);
    o  = fmaf(dtv, yU + yV, ob);

    dv = dn;
    dn = dnn;
  }
}

extern "C" void kernel_launch(void* const* d_in, const int* in_sizes, int n_in,
                              void* d_out, int out_size, void* d_ws, size_t ws_size,
                              hipStream_t stream) {
  (void)in_sizes; (void)n_in; (void)d_ws; (void)ws_size; (void)out_size;
  const float* times   = (const float*)d_in[0];
  const float* initial = (const float*)d_in[1];
  const float* Wi  = (const float*)d_in[2];
  const float* bi  = (const float*)d_in[3];
  const float* Wf0 = (const float*)d_in[4];
  const float* bf0 = (const float*)d_in[5];
  const float* Wf1 = (const float*)d_in[6];
  const float* bf1 = (const float*)d_in[7];
  const float* Wf2 = (const float*)d_in[8];
  const float* bf2 = (const float*)d_in[9];
  const float* Wf3 = (const float*)d_in[10];
  const float* bf3 = (const float*)d_in[11];
  const float* Wl  = (const float*)d_in[12];
  const float* bl  = (const float*)d_in[13];

  dim3 grid((BN * 16) / 256);  // 256 blocks -> 1 block/CU, 1 wave/SIMD
  dim3 block(256);
  hipLaunchKernelGGL(node_kernel, grid, block, 0, stream,
                     times, initial, Wi, bi, Wf0, bf0, Wf1, bf1,
                     Wf2, bf2, Wf3, bf3, Wl, bl, (float*)d_out);
}

// Round 6
// 397.990 us; speedup vs baseline: 1.6446x; 1.2670x over previous
//
#include <hip/hip_runtime.h>

#ifndef __has_builtin
#define __has_builtin(x) 0
#endif

// Problem constants (fixed by the reference):
constexpr int TN   = 1000;  // T
constexpr int BN   = 4096;  // B
constexpr int HID  = 32;    // hidden dim
constexpr int HH   = 15;    // func-net inner dim (padded to 16 in registers)
constexpr int OUTD = 8;     // output dim

__device__ __forceinline__ float fexp2(float x) {
#if __has_builtin(__builtin_amdgcn_exp2f)
  return __builtin_amdgcn_exp2f(x);
#else
  return exp2f(x);
#endif
}
__device__ __forceinline__ float frcp(float x) {
#if __has_builtin(__builtin_amdgcn_rcpf)
  return __builtin_amdgcn_rcpf(x);
#else
  return 1.0f / x;
#endif
}

// row_ror:K within the 16-lane DPP row (intrinsic: compiler-managed hazards;
// used at init and for the one o-combine in the loop).
template <int K>
__device__ __forceinline__ float rotk(float x) {
  if constexpr (K == 0) {
    return x;
  } else {
    return __int_as_float(
        __builtin_amdgcn_mov_dpp(__float_as_int(x), 0x120 + K, 0xF, 0xF, true));
  }
}

// ---- fused rotate+FMA (round-5 proven discipline) ----
// All loop DPPs are volatile asm (mutual program order preserved) and the
// textually-first DPP reading a freshly-written source carries s_nop 1
// (VALU-write -> DPP-read needs 2 wait states; worst case the producer is
// immediately before: producer; s_nop 1; dpp = 2 states).
#define FMAC_DPP(acc, src, w, K)                                            \
  asm volatile("v_fmac_f32_dpp %0, %1, %2 row_ror:" #K                      \
               " row_mask:0xf bank_mask:0xf"                                \
               : "+v"(acc) : "v"(src), "v"(w))

#define MUL_DPP(dst, src, w, K)                                             \
  asm volatile("v_mul_f32_dpp %0, %1, %2 row_ror:" #K                       \
               " row_mask:0xf bank_mask:0xf"                                \
               : "=v"(dst) : "v"(src), "v"(w))

#define MUL_DPP_NOP(dst, src, w, K)                                         \
  asm volatile("s_nop 1\n\t"                                                \
               "v_mul_f32_dpp %0, %1, %2 row_ror:" #K                       \
               " row_mask:0xf bank_mask:0xf"                                \
               : "=v"(dst) : "v"(src), "v"(w))

#define PIN(x) asm volatile("" : "+v"(x))

#define REP16(M) M(0) M(1) M(2) M(3) M(4) M(5) M(6) M(7) \
                 M(8) M(9) M(10) M(11) M(12) M(13) M(14) M(15)
#define REP8(M) M(0) M(1) M(2) M(3) M(4) M(5) M(6) M(7)

// 16 lanes per batch row. 4096*16 = 65536 threads = 1024 waves = 1 wave/SIMD.
//
// ROUND 6: the 32-dim hidden state h is eliminated from the loop. The loop
// only consumed h through a0 = CS*(h@Wf0+bf0) and o = h@Wl+bl; both follow
// exact linear recurrences driven by r2 = 1/(exp2(a2)+1):
//   a0 += dt*(ba + r2 @ Ma),  Ma = -2CS*(Wf3@Wf0) (15x15), ba = CS*fcol@Wf0
//   o  += dt*(boy + r2 @ Mo),  Mo = -2*(Wf3@Wl),  boy = fcol@Wl
// where fcol = bf3 + colsum(Wf3) (the z2 = 1-2*r2 affine absorption).
// This composes layer3 with layer0: per-step DPP MACs drop 112 -> 52.
// The o-sum is additionally split across lane halves (o is duplicated in
// lanes q and q+8): each half sums 8 of 16 rotations, combined by one
// row_ror:8 add (the two halves' p-sets partition [0,16) for either DPP
// direction, and the combine is commutative -> both halves stay
// bit-identical).
__global__ __launch_bounds__(256)
__attribute__((amdgpu_waves_per_eu(1, 1)))
void node_kernel(
    const float* __restrict__ times, const float* __restrict__ initial,
    const float* __restrict__ Wi, const float* __restrict__ bi,
    const float* __restrict__ Wf0, const float* __restrict__ bf0,
    const float* __restrict__ Wf1, const float* __restrict__ bf1,
    const float* __restrict__ Wf2, const float* __restrict__ bf2,
    const float* __restrict__ Wf3, const float* __restrict__ bf3,
    const float* __restrict__ Wl, const float* __restrict__ bl,
    float* __restrict__ out) {
  __shared__ float sdt[TN + 2];   // padded: sdt[TN-1..TN+1] = 0, no clamps

  const int tid = blockIdx.x * 256 + threadIdx.x;
  const int row = tid >> 4;   // batch row, 0..4095
  const int q   = tid & 15;   // position within the 16-lane ring
  const int c   = q & 7;      // owned output column

  for (int i = threadIdx.x; i < TN + 2; i += 256) {
    float d = 0.f;
    if (i < TN - 1) d = times[i + 1] - times[i];
    sdt[i] = d;
  }

  // DPP direction probe: correct under either hardware rotate convention.
  int s1 = __builtin_amdgcn_mov_dpp(q, 0x121, 0xF, 0xF, true);
  const int dir = (s1 == ((q + 1) & 15)) ? 1 : -1;

  const bool qv = (q < HH);

  // tanh(a) = 1 - 2*r with r = 1/(exp2(a*CS)+1), CS = 2*log2(e).
  const float CS = 2.8853900817779268f;

  // ---- composed-weight precompute ----
  // fcol[e] = bf3[e] + colsum_p Wf3[p][e]
  float fcol[HID];
#pragma unroll
  for (int e = 0; e < HID; ++e) {
    float s = bf3[e];
#pragma unroll
    for (int p = 0; p < HH; ++p) s += Wf3[p * HID + e];
    fcol[e] = s;
  }
  // w0c[e] = Wf0[e][q] (zeroed for invalid q), wlc[e] = Wl[e][c]
  float w0c[HID], wlc[HID];
#pragma unroll
  for (int e = 0; e < HID; ++e) {
    w0c[e] = qv ? Wf0[e * HH + q] : 0.f;
    wlc[e] = Wl[e * OUTD + c];
  }
  float ba = 0.f, boy = 0.f;
#pragma unroll 4
  for (int e = 0; e < HID; ++e) {
    ba  = fmaf(fcol[e], w0c[e], ba);
    boy = fmaf(fcol[e], wlc[e], boy);
  }
  ba *= CS;

  // layer1/2 absorbed biases
  float cs1 = 0.f, cs2 = 0.f;
  if (qv) {
#pragma unroll
    for (int e = 0; e < HH; ++e) {
      cs1 += Wf1[e * HH + q];
      cs2 += Wf2[e * HH + q];
    }
  }
  float b1s = qv ? (bf1[q] + cs1) * CS : 0.f;
  float b2s = qv ? (bf2[q] + cs2) * CS : 0.f;
  PIN(b1s); PIN(b2s);

  // --- weight registers, pre-rotated into ring order ---
  // w1_k = -2CS*Wf1[p(k)][q], w2_k = -2CS*Wf2[p(k)][q]
  // ma_k = -2CS*(Wf3@Wf0)[p(k)][q]   (a0-recurrence)
  // wo_k = -2*(Wf3@Wl)[p(k)][c], k=0..7 only (o-split)
#define DECLW(k) float w1_##k, w2_##k, ma_##k;
  REP16(DECLW)
#undef DECLW
#define DECLO(k) float wo_##k;
  REP8(DECLO)
#undef DECLO

#define INITW(k)                                                        \
  {                                                                     \
    int p = (q + dir * (k)) & 15;                                       \
    bool pv = (p < HH);                                                 \
    w1_##k = (pv && qv) ? -2.f * CS * Wf1[p * HH + q] : 0.f;            \
    w2_##k = (pv && qv) ? -2.f * CS * Wf2[p * HH + q] : 0.f;            \
    float s_ = 0.f;                                                     \
    if (pv && qv) {                                                     \
      _Pragma("unroll 4") for (int e = 0; e < HID; ++e)                 \
          s_ = fmaf(Wf3[p * HID + e], w0c[e], s_);                      \
    }                                                                   \
    ma_##k = -2.f * CS * s_;                                            \
    PIN(w1_##k); PIN(w2_##k); PIN(ma_##k);                              \
  }
  REP16(INITW)
#undef INITW

#define INITWO(k)                                                       \
  {                                                                     \
    int p = (q + dir * (k)) & 15;                                       \
    float s_ = 0.f;                                                     \
    if (p < HH) {                                                       \
      _Pragma("unroll 4") for (int e = 0; e < HID; ++e)                 \
          s_ = fmaf(Wf3[p * HID + e], wlc[e], s_);                      \
    }                                                                   \
    wo_##k = -2.f * s_;                                                 \
    PIN(wo_##k);                                                        \
  }
  REP8(INITWO)
#undef INITWO

  // --- h(0) = initial @ Wi + bi ; lane owns components 2q, 2q+1 (init only)
  float h0 = bi[2 * q + 0];
  float h1 = bi[2 * q + 1];
  {
    const float* ini = initial + (size_t)row * 16;
#pragma unroll
    for (int i = 0; i < 16; ++i) {
      float x = ini[i];
      h0 = fmaf(x, Wi[i * HID + 2 * q + 0], h0);
      h1 = fmaf(x, Wi[i * HID + 2 * q + 1], h1);
    }
  }

  // --- a0(0) = CS*(h(0) @ Wf0 + bf0)[q], via the rotation ring (intrinsics)
  float aa = qv ? bf0[q] : 0.f;
#define A0K(k)                                                  \
  {                                                             \
    float a_ = rotk<k>(h0);                                     \
    float b_ = rotk<k>(h1);                                     \
    int p = (q + dir * (k)) & 15;                               \
    if (qv) {                                                   \
      aa = fmaf(a_, Wf0[(2 * p + 0) * HH + q], aa);             \
      aa = fmaf(b_, Wf0[(2 * p + 1) * HH + q], aa);             \
    }                                                           \
  }
  REP16(A0K)
#undef A0K
  float a0 = CS * aa;

  // --- o(0) = h(0) @ Wl + bl (duplicated across lane halves)
  float o = bl[c];
#define O0K(k)                                                  \
  {                                                             \
    float a_ = rotk<k>(h0);                                     \
    float b_ = rotk<k>(h1);                                     \
    int p = (q + dir * (k)) & 15;                               \
    o = fmaf(a_, Wl[(2 * p + 0) * OUTD + c], o);                \
    o = fmaf(b_, Wl[(2 * p + 1) * OUTD + c], o);                \
  }
  REP16(O0K)
#undef O0K

  unsigned obyte = ((unsigned)row * (unsigned)(TN * OUTD) + (unsigned)c) * 4u;
  char* outb = (char*)out;

  __syncthreads();
  float dv = sdt[0];
  float dn = sdt[1];

#pragma unroll 1
  for (int t = 0; t < TN; ++t) {
    float dnn = sdt[t + 2];   // padded table: no clamp

    // store o(t): value finalized last iteration -> latency fully hidden
    *(float*)(outb + obyte) = o;
    obyte += OUTD * 4;

    float dtv = dv;
    float a0b = fmaf(dtv, ba, a0);
    float ob  = fmaf(dtv, boy, o);

    // --- r0 = sigma(a0); a0 is already in CS space
    float r0 = frcp(fexp2(a0) + 1.0f);

    // --- layer1: 4 chains over 16 rotations of r0 (first DPP guarded)
    float s_a = fmaf(r0, w1_0, b1s);
    float s_b, s_c, s_d;
    MUL_DPP_NOP(s_b, r0, w1_1, 1);
    MUL_DPP(s_c, r0, w1_2, 2);
    MUL_DPP(s_d, r0, w1_3, 3);
#define L1S(k, acc) FMAC_DPP(acc, r0, w1_##k, k);
    L1S(4, s_a)  L1S(5, s_b)  L1S(6, s_c)  L1S(7, s_d)
    L1S(8, s_a)  L1S(9, s_b)  L1S(10, s_c) L1S(11, s_d)
    L1S(12, s_a) L1S(13, s_b) L1S(14, s_c) L1S(15, s_d)
#undef L1S
    float a1 = (s_a + s_b) + (s_c + s_d);
    float r1 = frcp(fexp2(a1) + 1.0f);

    // --- layer2
    float u_a = fmaf(r1, w2_0, b2s);
    float u_b, u_c, u_d;
    MUL_DPP_NOP(u_b, r1, w2_1, 1);
    MUL_DPP(u_c, r1, w2_2, 2);
    MUL_DPP(u_d, r1, w2_3, 3);
#define L2S(k, acc) FMAC_DPP(acc, r1, w2_##k, k);
    L2S(4, u_a)  L2S(5, u_b)  L2S(6, u_c)  L2S(7, u_d)
    L2S(8, u_a)  L2S(9, u_b)  L2S(10, u_c) L2S(11, u_d)
    L2S(12, u_a) L2S(13, u_b) L2S(14, u_c) L2S(15, u_d)
#undef L2S
    float a2 = (u_a + u_b) + (u_c + u_d);
    float r2 = frcp(fexp2(a2) + 1.0f);

    // --- fused state updates, all driven by r2 (manually interleaved):
    //   a0-delta: 16 rotations with ma (4 chains y_a..y_d)
    //   o-delta:   8 rotations with wo (2 chains p_a,p_b; half-sum)
    float y_a = r2 * ma_0;
    float p_a = r2 * wo_0;
    float y_b, y_c, y_d, p_b;
    MUL_DPP_NOP(y_b, r2, ma_1, 1);
    MUL_DPP(p_b, r2, wo_1, 1);
    MUL_DPP(y_c, r2, ma_2, 2);
    MUL_DPP(y_d, r2, ma_3, 3);
    FMAC_DPP(p_a, r2, wo_2, 2);
    FMAC_DPP(p_b, r2, wo_3, 3);
    FMAC_DPP(y_a, r2, ma_4, 4);
    FMAC_DPP(p_a, r2, wo_4, 4);
    FMAC_DPP(y_b, r2, ma_5, 5);
    FMAC_DPP(p_b, r2, wo_5, 5);
    FMAC_DPP(y_c, r2, ma_6, 6);
    FMAC_DPP(p_a, r2, wo_6, 6);
    FMAC_DPP(y_d, r2, ma_7, 7);
    FMAC_DPP(p_b, r2, wo_7, 7);
    FMAC_DPP(y_a, r2, ma_8, 8);
    FMAC_DPP(y_b, r2, ma_9, 9);
    FMAC_DPP(y_c, r2, ma_10, 10);
    FMAC_DPP(y_d, r2, ma_11, 11);
    FMAC_DPP(y_a, r2, ma_12, 12);
    FMAC_DPP(y_b, r2, ma_13, 13);
    FMAC_DPP(y_c, r2, ma_14, 14);
    FMAC_DPP(y_d, r2, ma_15, 15);

    float ya   = (y_a + y_b) + (y_c + y_d);
    float osum = p_a + p_b;
    float comb = osum + rotk<8>(osum);   // intrinsic: compiler-managed hazard
    a0 = fmaf(dtv, ya, a0b);
    o  = fmaf(dtv, comb, ob);

    dv = dn;
    dn = dnn;
  }
}

extern "C" void kernel_launch(void* const* d_in, const int* in_sizes, int n_in,
                              void* d_out, int out_size, void* d_ws, size_t ws_size,
                              hipStream_t stream) {
  (void)in_sizes; (void)n_in; (void)d_ws; (void)ws_size; (void)out_size;
  const float* times   = (const float*)d_in[0];
  const float* initial = (const float*)d_in[1];
  const float* Wi  = (const float*)d_in[2];
  const float* bi  = (const float*)d_in[3];
  const float* Wf0 = (const float*)d_in[4];
  const float* bf0 = (const float*)d_in[5];
  const float* Wf1 = (const float*)d_in[6];
  const float* bf1 = (const float*)d_in[7];
  const float* Wf2 = (const float*)d_in[8];
  const float* bf2 = (const float*)d_in[9];
  const float* Wf3 = (const float*)d_in[10];
  const float* bf3 = (const float*)d_in[11];
  const float* Wl  = (const float*)d_in[12];
  const float* bl  = (const float*)d_in[13];

  dim3 grid((BN * 16) / 256);  // 256 blocks -> 1 block/CU, 1 wave/SIMD
  dim3 block(256);
  hipLaunchKernelGGL(node_kernel, grid, block, 0, stream,
                     times, initial, Wi, bi, Wf0, bf0, Wf1, bf1,
                     Wf2, bf2, Wf3, bf3, Wl, bl, (float*)d_out);
}